// Round 7
// baseline (119.819 us; speedup 1.0000x reference)
//
#include <hip/hip_runtime.h>

#define K_SPARSE 64
#define COLS     4096
#define NTHREADS 256
#define EPT      (COLS / NTHREADS)   // 16 elements per thread
#define VPT      (EPT / 4)           // 4 float4 per thread
#define NREP     8                   // histogram replicas (contention fix)
#define RPB      8                   // rows per block (persistent, prefetch-pipelined)

typedef float nfloat4 __attribute__((ext_vector_type(4)));  // native vec for nt-store

// Order-preserving fp32 -> uint32 mapping (ascending float order == ascending uint order)
__device__ __forceinline__ unsigned mapf(unsigned b) {
    return (b & 0x80000000u) ? ~b : (b | 0x80000000u);
}
__device__ __forceinline__ float unmapf(unsigned u) {
    unsigned b = (u & 0x80000000u) ? (u ^ 0x80000000u) : ~u;
    return __uint_as_float(b);
}

__global__ __launch_bounds__(NTHREADS)
void ksparse_rowsel(const float* __restrict__ x, float* __restrict__ out, int rows)
{
    const int t    = threadIdx.x;
    const int lane = t & 63;
    const int w    = t >> 6;          // wave id 0..3; wave w owns bins w*64..w*64+63
    const int rep  = t & (NREP - 1);

    // Replicated histograms: hist[r][b] at word offset r*257+b -> bank (r+b)&31,
    // so the same bin in different replicas never shares a bank.
    __shared__ unsigned hist[NREP][257];
    __shared__ unsigned wtot[4];
    __shared__ unsigned s_prefix, s_target;

#pragma unroll
    for (int r = 0; r < NREP; ++r) hist[r][t] = 0u;
    __syncthreads();

    const int row0    = blockIdx.x * RPB;
    const int row_end = min(row0 + RPB, rows);
    if (row0 >= rows) return;

    const float4* __restrict__ xr =
        reinterpret_cast<const float4*>(x) + (size_t)row0 * (COLS / 4) + t;
    nfloat4* __restrict__ orow =
        reinterpret_cast<nfloat4*>(out) + (size_t)row0 * (COLS / 4) + t;

    // Prologue: load first row.
    float4 cur[VPT];
#pragma unroll
    for (int i = 0; i < VPT; ++i) cur[i] = xr[i * NTHREADS];

    for (int row = row0; row < row_end; ++row) {
        // Map current row to sortable uints (cur dies here).
        unsigned u[EPT];
#pragma unroll
        for (int i = 0; i < VPT; ++i) {
            u[i * 4 + 0] = mapf(__float_as_uint(cur[i].x));
            u[i * 4 + 1] = mapf(__float_as_uint(cur[i].y));
            u[i * 4 + 2] = mapf(__float_as_uint(cur[i].z));
            u[i * 4 + 3] = mapf(__float_as_uint(cur[i].w));
        }

        // Issue next row's loads NOW; first use is after the select, so the
        // HBM latency hides under ~1us of LDS/VALU select work (T14 pattern).
        const bool has_next = (row + 1 < row_end);
        float4 nxt[VPT];
        if (has_next) {
            const float4* xn = xr + (COLS / 4);
#pragma unroll
            for (int i = 0; i < VPT; ++i) nxt[i] = xn[i * NTHREADS];
        }

        // ---- 4-pass MSB-first radix select (exact kth = sorted[n-1-K]) ----
        // Pass 0 uses compile-time prefix/target, so s_prefix/s_target never
        // need re-initialization between rows (they are written only after
        // B1 of pass 0, which orders against the previous row's readers).
        unsigned high_mask = 0u;
#pragma unroll
        for (int p = 0; p < 4; ++p) {
            const int shift = 24 - 8 * p;
            const unsigned prefix = (p == 0) ? 0u : s_prefix;
            const unsigned target = (p == 0) ? (unsigned)K_SPARSE : s_target;

#pragma unroll
            for (int i = 0; i < EPT; ++i) {
                const bool m = (p == 0) || ((u[i] & high_mask) == prefix);
                if (m) atomicAdd(&hist[rep][(u[i] >> shift) & 0xFFu], 1u);
            }
            __syncthreads();                 // B1: all atomics for this pass done

            // Thread t owns bin t: merge replicas, then zero them (only this
            // thread ever reads bin t, so zeroing needs no extra barrier).
            unsigned tot = 0;
#pragma unroll
            for (int r = 0; r < NREP; ++r) { tot += hist[r][t]; hist[r][t] = 0u; }

            // Wave-level inclusive SUFFIX scan over the wave's 64 bins.
            unsigned s = tot;
#pragma unroll
            for (int off = 1; off < 64; off <<= 1) {
                unsigned v = __shfl_down(s, off, 64);
                if (lane + off < 64) s += v;
            }
            if (lane == 0) wtot[w] = s;      // wave total
            unsigned s_next = __shfl_down(s, 1, 64);
            __syncthreads();                 // B2: wtot visible

            unsigned later = 0;
#pragma unroll
            for (int ww = 0; ww < 4; ++ww) if (ww > w) later += wtot[ww];

            const unsigned Sb  = s + later;                               // S[t]
            const unsigned Sb1 = (lane < 63) ? (s_next + later) : later;  // S[t+1]
            if (Sb1 <= target && target < Sb) {   // exactly one thread
                s_prefix = prefix | ((unsigned)t << shift);
                s_target = target - Sb1;
            }
            high_mask |= (0xFFu << shift);
            __syncthreads();                 // B3: selection visible
        }

        const float kth = unmapf(s_prefix);  // exact threshold bit pattern

        // Masked store (nontemporal: output is never re-read; keep L2/L3
        // for the input stream).
#pragma unroll
        for (int i = 0; i < VPT; ++i) {
            nfloat4 o;
            float fx;
            fx = unmapf(u[i * 4 + 0]); o.x = (fx > kth) ? fx : 0.0f;
            fx = unmapf(u[i * 4 + 1]); o.y = (fx > kth) ? fx : 0.0f;
            fx = unmapf(u[i * 4 + 2]); o.z = (fx > kth) ? fx : 0.0f;
            fx = unmapf(u[i * 4 + 3]); o.w = (fx > kth) ? fx : 0.0f;
            __builtin_nontemporal_store(o, &orow[i * NTHREADS]);
        }

        xr   += COLS / 4;
        orow += COLS / 4;
        if (has_next) {
#pragma unroll
            for (int i = 0; i < VPT; ++i) cur[i] = nxt[i];  // waitcnt lands here
        }
    }
}

extern "C" void kernel_launch(void* const* d_in, const int* in_sizes, int n_in,
                              void* d_out, int out_size, void* d_ws, size_t ws_size,
                              hipStream_t stream) {
    const float* x = (const float*)d_in[0];
    float* out = (float*)d_out;
    const int rows = in_sizes[0] / COLS;
    const int blocks = (rows + RPB - 1) / RPB;
    ksparse_rowsel<<<blocks, NTHREADS, 0, stream>>>(x, out, rows);
}

// Round 9
// 74.198 us; speedup vs baseline: 1.6149x; 1.6149x over previous
//
#include <hip/hip_runtime.h>

#define K_SPARSE 64
#define COLS     4096
#define NTHREADS 256
#define EPT      (COLS / NTHREADS)   // 16 elements per thread
#define VPT      (EPT / 4)           // 4 float4 per thread
#define LIST_CAP 4104                // 4096 candidates max + pad for b128 tail reads

typedef float    nfloat4 __attribute__((ext_vector_type(4)));
typedef unsigned nuint4  __attribute__((ext_vector_type(4)));

// Order-preserving fp32 -> uint32 mapping (ascending float order == ascending uint order)
__device__ __forceinline__ unsigned mapf(unsigned b) {
    return (b & 0x80000000u) ? ~b : (b | 0x80000000u);
}
__device__ __forceinline__ float unmapf(unsigned u) {
    unsigned b = (u & 0x80000000u) ? (u ^ 0x80000000u) : ~u;
    return __uint_as_float(b);
}

__global__ __launch_bounds__(NTHREADS)
void ksparse_select(const float* __restrict__ x, float* __restrict__ out, int rows)
{
    const int row = blockIdx.x;
    if (row >= rows) return;
    const int t    = threadIdx.x;
    const int lane = t & 63;
    const int w    = t >> 6;

    __shared__ __align__(16) unsigned list[LIST_CAP];
    __shared__ unsigned wtot[4];
    __shared__ unsigned s_kth;

    const float4* __restrict__ xrow =
        reinterpret_cast<const float4*>(x) + (size_t)row * (COLS / 4);
    nfloat4* __restrict__ orow =
        reinterpret_cast<nfloat4*>(out) + (size_t)row * (COLS / 4);

    // Whole row into registers: original floats (for the final masked store)
    // and order-mapped uints (for exact selection).
    float4   cur[VPT];
    unsigned u[EPT];
#pragma unroll
    for (int i = 0; i < VPT; ++i) cur[i] = xrow[t + i * NTHREADS];
#pragma unroll
    for (int i = 0; i < VPT; ++i) {
        u[i * 4 + 0] = mapf(__float_as_uint(cur[i].x));
        u[i * 4 + 1] = mapf(__float_as_uint(cur[i].y));
        u[i * 4 + 2] = mapf(__float_as_uint(cur[i].z));
        u[i * 4 + 3] = mapf(__float_as_uint(cur[i].w));
    }

    // --- Phase 1: threshold rung ladder (exact for any input; for N(0,1)
    // the first rung T=1.9 yields c ~ 118 per row and always suffices).
    // Mapped-domain constants: mapf(1.9f)=0xBFF33333, mapf(0.9f)=0xBF666666,
    // mapf(-3.4e38f)~=0x00800000, 0 = below every finite value.
    unsigned uT = 0, cnt = 0, base = 0, c = 0;
    for (int r = 0; r < 4; ++r) {
        uT = (r == 0) ? 0xBFF33333u
           : (r == 1) ? 0xBF666666u
           : (r == 2) ? 0x00800000u : 0u;
        cnt = 0;
#pragma unroll
        for (int i = 0; i < EPT; ++i) cnt += (u[i] > uT) ? 1u : 0u;

        // Wave-level inclusive prefix scan of per-thread counts (no barriers).
        unsigned s = cnt;
#pragma unroll
        for (int off = 1; off < 64; off <<= 1) {
            unsigned v = __shfl_up(s, off, 64);
            if (lane >= off) s += v;
        }
        if (lane == 63) wtot[w] = s;   // wave total
        __syncthreads();               // B1: wtot visible
        const unsigned c0 = wtot[0], c1 = wtot[1], c2 = wtot[2], c3 = wtot[3];
        c = c0 + c1 + c2 + c3;
        if (c >= K_SPARSE + 1 || r == 3) {
            unsigned wbase = (w > 0 ? c0 : 0u) + (w > 1 ? c1 : 0u) + (w > 2 ? c2 : 0u);
            base = wbase + s - cnt;    // exclusive prefix = block-wide offset
            break;
        }
        __syncthreads();               // B1b: all read wtot before next rung rewrites
    }

    // --- Phase 2: compact candidates (u > uT) to LDS at prefix offsets. No atomics.
    unsigned pos = base;
#pragma unroll
    for (int i = 0; i < EPT; ++i) {
        if (u[i] > uT) list[pos++] = u[i];
    }
    if (t < 8) list[c + t] = 0u;       // pad so b128 tail reads see neutral values
    __syncthreads();                   // B2: list complete

    // --- Phase 3: exact rank-(K_SPARSE) select among c candidates.
    // kth value v*: greater(v*) <= 64 < greater(v*) + equal(v*)  (tie-exact).
    const int nq = (int)((c + 3) >> 2);
    const nuint4* listv = reinterpret_cast<const nuint4*>(list);
    for (int j = t; j < (int)c; j += NTHREADS) {
        const unsigned vj = list[j];
        unsigned g = 0, e = 0;
        for (int q = 0; q < nq; ++q) {
            const nuint4 ql = listv[q];        // broadcast read: all lanes same addr
            g += (ql.x > vj) + (ql.y > vj) + (ql.z > vj) + (ql.w > vj);
            e += (ql.x == vj) + (ql.y == vj) + (ql.z == vj) + (ql.w == vj);
        }
        if (g <= (unsigned)K_SPARSE && (unsigned)K_SPARSE < g + e)
            s_kth = vj;                        // unique value; benign same-value race
    }
    __syncthreads();                   // B3: s_kth visible

    const float kth = unmapf(s_kth);

    // --- Phase 4: masked nt-store from the original float registers
    // (float compare matches reference semantics exactly, incl. +-0).
#pragma unroll
    for (int i = 0; i < VPT; ++i) {
        nfloat4 o;
        o.x = (cur[i].x > kth) ? cur[i].x : 0.0f;
        o.y = (cur[i].y > kth) ? cur[i].y : 0.0f;
        o.z = (cur[i].z > kth) ? cur[i].z : 0.0f;
        o.w = (cur[i].w > kth) ? cur[i].w : 0.0f;
        __builtin_nontemporal_store(o, &orow[t + i * NTHREADS]);
    }
}

extern "C" void kernel_launch(void* const* d_in, const int* in_sizes, int n_in,
                              void* d_out, int out_size, void* d_ws, size_t ws_size,
                              hipStream_t stream) {
    const float* x = (const float*)d_in[0];
    float* out = (float*)d_out;
    const int rows = in_sizes[0] / COLS;
    ksparse_select<<<rows, NTHREADS, 0, stream>>>(x, out, rows);
}